// Round 6
// baseline (331.944 us; speedup 1.0000x reference)
//
#include <hip/hip_runtime.h>

// B=8, N=32, T=64, D=128, E=4, H=32, BT=512
// R15: free occupancy + serial-chain cuts. Six designs (R9-R14) all land at
// 186-221us kernel time with traffic 306-651MB, occ 10-40%, VGPR 64-256:
// latency-bound regime where waves/CU is the only lever that ever moved BW
// (R9 40% occ = best BW). R14 used (256,2) but its 52224B arena fits 3/CU
// (156672 <= 163840) -- free +50% TLP. Plus: P4 softmax fused into P3
// (row lives in a 16-lane group; 8 shfl_xor replace a barrier + LDS
// round-trip), and P8's x rows prefetched at end of P6 (latency drains
// during the P7 barrier). All other phase math verbatim from R14.
// Numerics: only softmax denominator association changes (16-lane tree).

typedef __bf16 bf16x8 __attribute__((ext_vector_type(8)));
typedef float  f32x4  __attribute__((ext_vector_type(4)));

static __device__ __forceinline__ unsigned short f2bf(float f) {
    unsigned u = __float_as_uint(f);
    u += 0x7fffu + ((u >> 16) & 1u);        // RNE
    return (unsigned short)(u >> 16);
}
static __device__ __forceinline__ float bf2f(unsigned short u) {
    return __uint_as_float(((unsigned)u) << 16);
}
static __device__ __forceinline__ unsigned pack2(float a, float b) {
    return (unsigned)f2bf(a) | ((unsigned)f2bf(b) << 16);
}

// ---------------------------------------------------------------------------
// Wfrag (16B chunks): [0,2048) Wq | [2048,4096) Wk | [4096,6144) Wv |
// [6144,8192) Theta | chunk 8192+: Cq=W1q@Wq (512), chunk 8704+: Ck=W1k@Wk (512).
// B-frag chunk (nt*4+ks)*64+lane holds B[k=j][n]: n = nt*16+(lane&15),
// j = ks*32+(lane>>4)*8 + (0..7).
// ---------------------------------------------------------------------------

__global__ __launch_bounds__(256) void k0_prep(
    const float* __restrict__ Wq, const float* __restrict__ Wk,
    const float* __restrict__ Wv, const float* __restrict__ Theta,
    const float* __restrict__ W1, unsigned short* __restrict__ Wfrag)
{
    const int tid = threadIdx.x;
    if (blockIdx.x < 32) {
        int gid = blockIdx.x * 256 + tid;      // 0..8191
        int g = gid >> 11, c = gid & 2047;
        int ntk = c >> 6, lane = c & 63;
        int i = (ntk >> 2) * 16 + (lane & 15);
        int j = (ntk & 3) * 32 + (lane >> 4) * 8;
        const float* src = (g == 0 ? Wq : g == 1 ? Wk : g == 2 ? Wv : Theta) + (size_t)i * 128 + j;
        float4 a = *(const float4*)(src);
        float4 b = *(const float4*)(src + 4);
        uint4 pk;
        pk.x = pack2(a.x, a.y); pk.y = pack2(a.z, a.w);
        pk.z = pack2(b.x, b.y); pk.w = pack2(b.z, b.w);
        *(uint4*)(Wfrag + (size_t)gid * 8) = pk;
    } else {
        // compose Cq = W1q@Wq, Ck = W1k@Wk
        int b2 = blockIdx.x - 32;              // 0..31
        int mat = b2 & 1;
        int hbase = (b2 >> 1) * 2;
        int hl = tid >> 7, col = tid & 127;
        int h = hbase + hl;
        const float* Wsel = mat ? Wk : Wq;
        const float* w1r = W1 + (size_t)h * 260 + mat * 128;
        float acc = 0.f;
        for (int i = 0; i < 128; ++i)
            acc = fmaf(w1r[i], Wsel[(size_t)i * 128 + col], acc);
        int nt = h >> 4;
        unsigned base = 65536u + (unsigned)mat * 4096u;   // shorts
        int lane = (h & 15) | (((col >> 3) & 3) << 4);
        int ks = col >> 5, vj = col & 7;
        Wfrag[base + (unsigned)((nt * 4 + ks) * 64 + lane) * 8 + vj] = f2bf(acc);
    }
}

// ===== fully fused: grid 512 (1 bt/block), 256 threads, 3 blocks/CU =========
// Arena (52224 B):
//  Qs[32][132] f32 @0        (Zfrag alias pre-proj, ThOut alias post-P7)
//  Ks[32][132] f32 @16896    (Sfrag alias post-P3)
//  Vs[32][136] bf16 @33792 | Lg[32][36] f32 @42496
//  hqL[32][34] bf16 @47104 | hkL[32][34] bf16 @49280
//  W1e_s @51456 | W2_s @51968 | maskrow @52096
__global__ __launch_bounds__(256, 3)
void gnn_all(const float* __restrict__ x, const float* __restrict__ edge,
             const float* __restrict__ A_prior, const unsigned char* __restrict__ pad_mask,
             const unsigned short* __restrict__ Wfrag, const float* __restrict__ Wfuse,
             const float* __restrict__ W1, const float* __restrict__ b1,
             const float* __restrict__ W2, const float* __restrict__ b2,
             const float* __restrict__ gma, const float* __restrict__ bta,
             const float* __restrict__ physw, const float* __restrict__ priorw,
             float* __restrict__ out)
{
    __shared__ __align__(16) unsigned char arena[52224];
    float*          Qs    = (float*)arena;
    unsigned short* Zfrag = (unsigned short*)arena;           // pre-projection
    float*          ThOut = Qs;                               // post-P7, stride 132
    float*          Ks    = (float*)(arena + 16896);
    unsigned short* Sfrag = (unsigned short*)(arena + 16896); // post-P3
    unsigned short* Vs    = (unsigned short*)(arena + 33792); // [32][136]
    float*          Lg    = (float*)(arena + 42496);          // [32][36]
    unsigned short* hqL   = (unsigned short*)(arena + 47104);
    unsigned short* hkL   = (unsigned short*)(arena + 49280);
    float4*         W1e_s = (float4*)(arena + 51456);
    float*          W2_s  = (float*)(arena + 51968);
    float*          maskrow = (float*)(arena + 52096);

    const int tid = threadIdx.x;
    const int bt  = blockIdx.x;
    const int b_  = bt >> 6, t_ = bt & 63;

    const float pw  = physw[0];
    const float rw_ = priorw[0];
    const float b2v = b2[0];
    const float wf0 = Wfuse[0], wf1 = Wfuse[1], wf2 = Wfuse[2],
                wf3 = Wfuse[3], wf4 = Wfuse[4];

    const int wv = tid >> 6, lane = tid & 63;
    const int quad = lane >> 4, col0 = lane & 15;
    const float b1lo = b1[col0], b1hi = b1[16 + col0];
    const int d0p = (tid & 31) * 4, ngp = tid >> 5;           // P6/P8 mapping
    const float4 g4  = *(const float4*)(gma + d0p);
    const float4 be4 = *(const float4*)(bta + d0p);

    // ---- early edge/prior loads (consumed in P3, hidden under projection);
    //      prior folded at arrival: 20 regs total ----
    const int mp = tid & 15, npg = tid >> 4;
    const int n0 = npg * 2, mA = mp, mB = mp + 16;
    float4 e4[2][2];
    float  prv[2][2];
#pragma unroll
    for (int r = 0; r < 2; ++r)
#pragma unroll
        for (int c = 0; c < 2; ++c) {
            int m = c ? mB : mA;
            e4[r][c] = *(const float4*)(edge + (((size_t)bt * 32 + (n0 + r)) * 32 + m) * 4);
            const float* pp = A_prior + (((size_t)bt * 32 + (n0 + r)) * 32 + m) * 5;
            float pr = pp[0]*wf0 + pp[1]*wf1 + pp[2]*wf2 + pp[3]*wf3 + pp[4]*wf4;
            if (!(fabsf(pr) < 1e30f)) pr = 0.f;
            pr = fmaxf(pr, 0.f);
            prv[r][c] = rw_ * __logf(pr + 1e-6f);
        }

    if (tid < 32) {
        W1e_s[tid] = *(const float4*)(W1 + (size_t)tid * 260 + 256);
        W2_s[tid]  = W2[tid];
        maskrow[tid] = pad_mask[b_ * 32 + tid] ? 1.f : 0.f;
    }

    // ---- Z staging: pack x -> bf16 A-frags (512 chunks in Qs region) ----
#pragma unroll
    for (int it2 = 0; it2 < 2; ++it2) {
        int f = tid + 256 * it2;                // chunk 0..511
        int lane9 = f & 63, tk = f >> 6;        // tk 0..7
        int nl = (tk >> 2) * 16 + (lane9 & 15); // token 0..31
        int d  = (tk & 3) * 32 + (lane9 >> 4) * 8;
        const float* xr = x + ((size_t)((b_ * 32 + nl) * 64 + t_)) * 128 + d;
        float4 a = *(const float4*)(xr);
        float4 b = *(const float4*)(xr + 4);
        uint4 pk;
        pk.x = pack2(a.x, a.y); pk.y = pack2(a.z, a.w);
        pk.z = pack2(b.x, b.y); pk.w = pack2(b.z, b.w);
        *(uint4*)(Zfrag + f * 8) = pk;
    }
    __syncthreads();

    // ---- A-frags to regs; barrier before Qs overwrite ----
    bf16x8 avZ[2][4];
#pragma unroll
    for (int tg = 0; tg < 2; ++tg)
#pragma unroll
        for (int ks = 0; ks < 4; ++ks)
            avZ[tg][ks] = *(const bf16x8*)(Zfrag + ((tg * 4 + ks) * 64 + lane) * 8);
    __syncthreads();

    const bf16x8* WfG = (const bf16x8*)Wfrag;    // all weights from L2-global
    const f32x4 zero = {0.f, 0.f, 0.f, 0.f};

    // ---- projection: per wave nt set {wv, wv+4, ..., wv+24} ----
#pragma unroll
    for (int k7 = 0; k7 < 7; ++k7) {
        const int nt = wv + k7 * 4;             // wave-uniform
        const int cb = ((nt < 24) ? nt * 256 : 8192 + (nt - 24) * 256) + lane;
        bf16x8 bw0 = WfG[cb];
        bf16x8 bw1 = WfG[cb + 64];
        bf16x8 bw2 = WfG[cb + 128];
        bf16x8 bw3 = WfG[cb + 192];
        f32x4 acc0 = zero, acc1 = zero;
        acc0 = __builtin_amdgcn_mfma_f32_16x16x32_bf16(avZ[0][0], bw0, acc0, 0, 0, 0);
        acc1 = __builtin_amdgcn_mfma_f32_16x16x32_bf16(avZ[1][0], bw0, acc1, 0, 0, 0);
        acc0 = __builtin_amdgcn_mfma_f32_16x16x32_bf16(avZ[0][1], bw1, acc0, 0, 0, 0);
        acc1 = __builtin_amdgcn_mfma_f32_16x16x32_bf16(avZ[1][1], bw1, acc1, 0, 0, 0);
        acc0 = __builtin_amdgcn_mfma_f32_16x16x32_bf16(avZ[0][2], bw2, acc0, 0, 0, 0);
        acc1 = __builtin_amdgcn_mfma_f32_16x16x32_bf16(avZ[1][2], bw2, acc1, 0, 0, 0);
        acc0 = __builtin_amdgcn_mfma_f32_16x16x32_bf16(avZ[0][3], bw3, acc0, 0, 0, 0);
        acc1 = __builtin_amdgcn_mfma_f32_16x16x32_bf16(avZ[1][3], bw3, acc1, 0, 0, 0);
#pragma unroll
        for (int tg = 0; tg < 2; ++tg) {
            const f32x4 acc = tg ? acc1 : acc0;
            const int tokb = tg * 16 + quad * 4;
#pragma unroll
            for (int reg = 0; reg < 4; ++reg) {
                int tok = tokb + reg;
                float v = acc[reg];
                if (nt < 8)       Qs[tok * 132 + nt * 16 + col0] = v;
                else if (nt < 16) Ks[tok * 132 + (nt - 8) * 16 + col0] = v;
                else if (nt < 24) Vs[tok * 136 + (nt - 16) * 16 + col0] = f2bf(v);
                else if (nt < 26) hqL[tok * 34 + (nt - 24) * 16 + col0] = f2bf(v + (nt == 24 ? b1lo : b1hi));
                else              hkL[tok * 34 + (nt - 26) * 16 + col0] = f2bf(v);
            }
        }
    }
    __syncthreads();

    // ---- P3 + fused softmax: logits in regs, row-reduce via 16-lane shfl,
    //      write ALPHA to Lg (one barrier; P4 phase + LDS round-trip gone) ----
    {
        const float* qa = Qs + n0 * 132;
        const float* qb = qa + 132;
        const float* ka = Ks + mA * 132;
        const float* kb = Ks + mB * 132;
        float a00 = 0.f, a01 = 0.f, a10 = 0.f, a11 = 0.f;
        for (int j = 0; j < 128; j += 4) {
            float4 kva = *(const float4*)(ka + j);
            float4 kvb = *(const float4*)(kb + j);
            float4 qva = *(const float4*)(qa + j);
            float4 qvb = *(const float4*)(qb + j);
            a00 = fmaf(qva.x, kva.x, fmaf(qva.y, kva.y, fmaf(qva.z, kva.z, fmaf(qva.w, kva.w, a00))));
            a01 = fmaf(qva.x, kvb.x, fmaf(qva.y, kvb.y, fmaf(qva.z, kvb.z, fmaf(qva.w, kvb.w, a01))));
            a10 = fmaf(qvb.x, kva.x, fmaf(qvb.y, kva.y, fmaf(qvb.z, kva.z, fmaf(qvb.w, kva.w, a10))));
            a11 = fmaf(qvb.x, kvb.x, fmaf(qvb.y, kvb.y, fmaf(qvb.z, kvb.z, fmaf(qvb.w, kvb.w, a11))));
        }
        float pacc[2][2] = {{0.f, 0.f}, {0.f, 0.f}};
#pragma unroll
        for (int h = 0; h < 32; ++h) {
            float4 we = W1e_s[h];
            float w2v = W2_s[h];
            float hq0 = bf2f(hqL[n0 * 34 + h]);
            float hq1 = bf2f(hqL[(n0 + 1) * 34 + h]);
            float hkA = bf2f(hkL[mA * 34 + h]);
            float hkB = bf2f(hkL[mB * 34 + h]);
#pragma unroll
            for (int r = 0; r < 2; ++r) {
                float hqv = r ? hq1 : hq0;
#pragma unroll
                for (int c = 0; c < 2; ++c) {
                    float hkv = c ? hkB : hkA;
                    float4 e = e4[r][c];
                    float he = fmaf(e.x, we.x, fmaf(e.y, we.y, fmaf(e.z, we.z, e.w * we.w)));
                    pacc[r][c] = fmaf(fmaxf(hqv + hkv + he, 0.f), w2v, pacc[r][c]);
                }
            }
        }
        float cont[2][2] = {{a00, a01}, {a10, a11}};
        float lg[2][2];
#pragma unroll
        for (int r = 0; r < 2; ++r)
#pragma unroll
            for (int c = 0; c < 2; ++c) {
                int n = n0 + r, m = c ? mB : mA;
                float v = cont[r][c] * 0.08838834764831845f
                        + pw * (pacc[r][c] + b2v) + prv[r][c];
                if (maskrow[n] != 0.f || maskrow[m] != 0.f) v = -1e9f;
                lg[r][c] = v;
            }
        // fused row softmax: row (n0+r) lives across the 16-lane mp-group
#pragma unroll
        for (int r = 0; r < 2; ++r) {
            float mx = fmaxf(lg[r][0], lg[r][1]);
#pragma unroll
            for (int off = 1; off < 16; off <<= 1)
                mx = fmaxf(mx, __shfl_xor(mx, off, 64));
            float e0 = __expf(lg[r][0] - mx);
            float e1 = __expf(lg[r][1] - mx);
            float s = e0 + e1;
#pragma unroll
            for (int off = 1; off < 16; off <<= 1)
                s += __shfl_xor(s, off, 64);
            float inv = 1.f / s;
            Lg[(n0 + r) * 36 + mA] = e0 * inv;
            Lg[(n0 + r) * 36 + mB] = e1 * inv;
        }
    }
    __syncthreads();

    const int rg = wv & 1, ch = wv >> 1;

    // ---- P6: spatial = alpha @ V (4 rows/thread) -> Sfrag bf16 A-frags ----
    float4 xpre[4];                 // P8 x prefetch (issued at end of P6)
    {
        const int vks = d0p >> 5, vq = (d0p >> 3) & 3, vj = d0p & 7;
        float sa[4][4] = {};
        for (int m = 0; m < 32; m += 4) {
            float alv[4][4];
#pragma unroll
            for (int r = 0; r < 4; ++r) {
                float4 t = *(const float4*)(Lg + (ngp * 4 + r) * 36 + m);
                alv[r][0] = t.x; alv[r][1] = t.y; alv[r][2] = t.z; alv[r][3] = t.w;
            }
#pragma unroll
            for (int mm = 0; mm < 4; ++mm) {
                uint2 vv = *(const uint2*)(Vs + (m + mm) * 136 + d0p);
                float v0 = bf2f((unsigned short)(vv.x & 0xffffu));
                float v1 = bf2f((unsigned short)(vv.x >> 16));
                float v2 = bf2f((unsigned short)(vv.y & 0xffffu));
                float v3 = bf2f((unsigned short)(vv.y >> 16));
#pragma unroll
                for (int r = 0; r < 4; ++r) {
                    float a = alv[r][mm];
                    sa[r][0] = fmaf(a, v0, sa[r][0]); sa[r][1] = fmaf(a, v1, sa[r][1]);
                    sa[r][2] = fmaf(a, v2, sa[r][2]); sa[r][3] = fmaf(a, v3, sa[r][3]);
                }
            }
        }
        // Sfrag aliases Ks (dead after P3)
#pragma unroll
        for (int r = 0; r < 4; ++r) {
            int nloc = ngp * 4 + r;
            int tg = nloc >> 4, nl = nloc & 15;
            unsigned short* sp = Sfrag + ((tg * 4 + vks) * 64 + vq * 16 + nl) * 8 + vj;
            sp[0] = f2bf(sa[r][0]); sp[1] = f2bf(sa[r][1]);
            sp[2] = f2bf(sa[r][2]); sp[3] = f2bf(sa[r][3]);
        }
        // issue P8's x loads now; latency drains during the P7 barrier
#pragma unroll
        for (int r = 0; r < 4; ++r)
            xpre[r] = *(const float4*)(x + ((size_t)((b_ * 32 + (ngp * 4 + r)) * 64 + t_)) * 128 + d0p);
    }
    __syncthreads();

    // ---- P7: Theta MFMA -> ThOut (alias Qs, stride 132); B-frags loaded
    //      inline per nt (transient 16 regs; L2-hit) ----
    {
        f32x4 aT[4] = {zero, zero, zero, zero};
        bf16x8 av0 = *(const bf16x8*)(Sfrag + ((rg * 4 + 0) * 64 + lane) * 8);
        bf16x8 av1 = *(const bf16x8*)(Sfrag + ((rg * 4 + 1) * 64 + lane) * 8);
        bf16x8 av2 = *(const bf16x8*)(Sfrag + ((rg * 4 + 2) * 64 + lane) * 8);
        bf16x8 av3 = *(const bf16x8*)(Sfrag + ((rg * 4 + 3) * 64 + lane) * 8);
#pragma unroll
        for (int nt = 0; nt < 4; ++nt) {
            const int cb = 6144 + ((ch * 4 + nt) * 4) * 64 + lane;
            bf16x8 t0 = WfG[cb];
            bf16x8 t1 = WfG[cb + 64];
            bf16x8 t2 = WfG[cb + 128];
            bf16x8 t3 = WfG[cb + 192];
            aT[nt] = __builtin_amdgcn_mfma_f32_16x16x32_bf16(av0, t0, aT[nt], 0, 0, 0);
            aT[nt] = __builtin_amdgcn_mfma_f32_16x16x32_bf16(av1, t1, aT[nt], 0, 0, 0);
            aT[nt] = __builtin_amdgcn_mfma_f32_16x16x32_bf16(av2, t2, aT[nt], 0, 0, 0);
            aT[nt] = __builtin_amdgcn_mfma_f32_16x16x32_bf16(av3, t3, aT[nt], 0, 0, 0);
        }
#pragma unroll
        for (int nt = 0; nt < 4; ++nt) {
            int colc = ch * 64 + nt * 16 + col0;
#pragma unroll
            for (int reg = 0; reg < 4; ++reg)
                ThOut[(rg * 16 + quad * 4 + reg) * 132 + colc] = aT[nt][reg];
        }
    }
    __syncthreads();

    // ---- P8: y = x + ThOut; LayerNorm; mask; store (4 rows/thread) ----
    {
#pragma unroll
        for (int r = 0; r < 4; ++r) {
            int nloc = ngp * 4 + r;
            float4 z  = xpre[r];
            float4 th = *(const float4*)(ThOut + nloc * 132 + d0p);
            float y0 = th.x + z.x, y1 = th.y + z.y, y2 = th.z + z.z, y3 = th.w + z.w;
            float s  = (y0 + y1) + (y2 + y3);
            float s2 = (y0*y0 + y1*y1) + (y2*y2 + y3*y3);
#pragma unroll
            for (int off = 1; off < 32; off <<= 1) {
                s  += __shfl_xor(s,  off, 64);
                s2 += __shfl_xor(s2, off, 64);
            }
            float mu   = s * 0.0078125f;
            float var  = s2 * 0.0078125f - mu * mu;
            float rstd = rsqrtf(var + 1e-5f);
            float msk  = (maskrow[nloc] != 0.f) ? 0.f : 1.f;
            float4 o;
            o.x = ((y0 - mu) * rstd * g4.x + be4.x) * msk;
            o.y = ((y1 - mu) * rstd * g4.y + be4.y) * msk;
            o.z = ((y2 - mu) * rstd * g4.z + be4.z) * msk;
            o.w = ((y3 - mu) * rstd * g4.w + be4.w) * msk;
            *(float4*)(out + ((size_t)((b_ * 32 + nloc) * 64 + t_)) * 128 + d0p) = o;
        }
    }
}

// ===========================================================================
extern "C" void kernel_launch(void* const* d_in, const int* in_sizes, int n_in,
                              void* d_out, int out_size, void* d_ws, size_t ws_size,
                              hipStream_t stream) {
    const float* x        = (const float*)d_in[0];
    const float* edge     = (const float*)d_in[1];
    const float* A_prior  = (const float*)d_in[2];
    const unsigned char* pad_mask = (const unsigned char*)d_in[3];
    const float* Wq       = (const float*)d_in[4];
    const float* Wk       = (const float*)d_in[5];
    const float* Wv       = (const float*)d_in[6];
    const float* Theta    = (const float*)d_in[7];
    const float* Wfuse    = (const float*)d_in[8];
    const float* W1       = (const float*)d_in[9];
    const float* b1       = (const float*)d_in[10];
    const float* W2       = (const float*)d_in[11];
    const float* b2       = (const float*)d_in[12];
    const float* gma      = (const float*)d_in[13];
    const float* bta      = (const float*)d_in[14];
    const float* physw    = (const float*)d_in[15];
    const float* priorw   = (const float*)d_in[16];
    float* out = (float*)d_out;

    unsigned short* Wfrag = (unsigned short*)d_ws;   // 147456 B (9216 chunks)

    k0_prep<<<dim3(64), dim3(256), 0, stream>>>(Wq, Wk, Wv, Theta, W1, Wfrag);
    gnn_all<<<dim3(512), dim3(256), 0, stream>>>(
        x, edge, A_prior, pad_mask, Wfrag, Wfuse,
        W1, b1, W2, b2, gma, bta, physw, priorw, out);
}

// Round 7
// 126.241 us; speedup vs baseline: 2.6294x; 2.6294x over previous
//
#include <hip/hip_runtime.h>

// B=8, N=32, T=64, D=128, E=4, H=32, BT=512
// R16: scalar-purge experiment on the R14 base (best persistent config,
// 188.8us kernel). Seven-round correlation: phantom FETCH/WRITE is a pure
// function of launch_bounds reg budget ((256,3)->84 regs->308/325MB in THREE
// different kernels; (256,2)->128->174-242/262; (256,1)->256->122/176) --
// scratch signature. R14 still holds constant-indexed local arrays (avZ, e4,
// prv, sa, alv, pacc); rule-#20 demotion under a reg bound is the last
// program-side suspect. This round: R14 verbatim structure, (256,2), grid
// 512, but ZERO aggregates in gnn_all -- every array is named scalars --
// plus R15's numerics-validated fused P3 softmax (one fewer barrier).
// Pre-committed read: phantom gone -> arrays were scratch; phantom intact ->
// floor is structural, declare ceiling next round.

typedef __bf16 bf16x8 __attribute__((ext_vector_type(8)));
typedef float  f32x4  __attribute__((ext_vector_type(4)));

static __device__ __forceinline__ unsigned short f2bf(float f) {
    unsigned u = __float_as_uint(f);
    u += 0x7fffu + ((u >> 16) & 1u);        // RNE
    return (unsigned short)(u >> 16);
}
static __device__ __forceinline__ float bf2f(unsigned short u) {
    return __uint_as_float(((unsigned)u) << 16);
}
static __device__ __forceinline__ unsigned pack2(float a, float b) {
    return (unsigned)f2bf(a) | ((unsigned)f2bf(b) << 16);
}

// ---------------------------------------------------------------------------
// Wfrag (16B chunks): [0,2048) Wq | [2048,4096) Wk | [4096,6144) Wv |
// [6144,8192) Theta | chunk 8192+: Cq=W1q@Wq (512), chunk 8704+: Ck=W1k@Wk (512).
// B-frag chunk (nt*4+ks)*64+lane holds B[k=j][n]: n = nt*16+(lane&15),
// j = ks*32+(lane>>4)*8 + (0..7).
// ---------------------------------------------------------------------------

__global__ __launch_bounds__(256) void k0_prep(
    const float* __restrict__ Wq, const float* __restrict__ Wk,
    const float* __restrict__ Wv, const float* __restrict__ Theta,
    const float* __restrict__ W1, unsigned short* __restrict__ Wfrag)
{
    const int tid = threadIdx.x;
    if (blockIdx.x < 32) {
        int gid = blockIdx.x * 256 + tid;      // 0..8191
        int g = gid >> 11, c = gid & 2047;
        int ntk = c >> 6, lane = c & 63;
        int i = (ntk >> 2) * 16 + (lane & 15);
        int j = (ntk & 3) * 32 + (lane >> 4) * 8;
        const float* src = (g == 0 ? Wq : g == 1 ? Wk : g == 2 ? Wv : Theta) + (size_t)i * 128 + j;
        float4 a = *(const float4*)(src);
        float4 b = *(const float4*)(src + 4);
        uint4 pk;
        pk.x = pack2(a.x, a.y); pk.y = pack2(a.z, a.w);
        pk.z = pack2(b.x, b.y); pk.w = pack2(b.z, b.w);
        *(uint4*)(Wfrag + (size_t)gid * 8) = pk;
    } else {
        // compose Cq = W1q@Wq, Ck = W1k@Wk
        int b2 = blockIdx.x - 32;              // 0..31
        int mat = b2 & 1;
        int hbase = (b2 >> 1) * 2;
        int hl = tid >> 7, col = tid & 127;
        int h = hbase + hl;
        const float* Wsel = mat ? Wk : Wq;
        const float* w1r = W1 + (size_t)h * 260 + mat * 128;
        float acc = 0.f;
        for (int i = 0; i < 128; ++i)
            acc = fmaf(w1r[i], Wsel[(size_t)i * 128 + col], acc);
        int nt = h >> 4;
        unsigned base = 65536u + (unsigned)mat * 4096u;   // shorts
        int lane = (h & 15) | (((col >> 3) & 3) << 4);
        int ks = col >> 5, vj = col & 7;
        Wfrag[base + (unsigned)((nt * 4 + ks) * 64 + lane) * 8 + vj] = f2bf(acc);
    }
}

// ===== fully fused: grid 512 (1 bt/block), 256 threads, (256,2) =============
// Arena (52224 B): identical to R14.
__global__ __launch_bounds__(256, 2)
void gnn_all(const float* __restrict__ x, const float* __restrict__ edge,
             const float* __restrict__ A_prior, const unsigned char* __restrict__ pad_mask,
             const unsigned short* __restrict__ Wfrag, const float* __restrict__ Wfuse,
             const float* __restrict__ W1, const float* __restrict__ b1,
             const float* __restrict__ W2, const float* __restrict__ b2,
             const float* __restrict__ gma, const float* __restrict__ bta,
             const float* __restrict__ physw, const float* __restrict__ priorw,
             float* __restrict__ out)
{
    __shared__ __align__(16) unsigned char arena[52224];
    float*          Qs    = (float*)arena;
    unsigned short* Zfrag = (unsigned short*)arena;           // pre-projection
    float*          ThOut = Qs;                               // post-P7, stride 132
    float*          Ks    = (float*)(arena + 16896);
    unsigned short* Sfrag = (unsigned short*)(arena + 16896); // post-P3
    unsigned short* Vs    = (unsigned short*)(arena + 33792); // [32][136]
    float*          Lg    = (float*)(arena + 42496);          // [32][36]
    unsigned short* hqL   = (unsigned short*)(arena + 47104);
    unsigned short* hkL   = (unsigned short*)(arena + 49280);
    float4*         W1e_s = (float4*)(arena + 51456);
    float*          W2_s  = (float*)(arena + 51968);
    float*          maskrow = (float*)(arena + 52096);

    const int tid = threadIdx.x;
    const int bt  = blockIdx.x;
    const int b_  = bt >> 6, t_ = bt & 63;

    const float pw  = physw[0];
    const float rw_ = priorw[0];
    const float b2v = b2[0];
    const float wf0 = Wfuse[0], wf1 = Wfuse[1], wf2 = Wfuse[2],
                wf3 = Wfuse[3], wf4 = Wfuse[4];

    const int wv = tid >> 6, lane = tid & 63;
    const int quad = lane >> 4, col0 = lane & 15;
    const float b1lo = b1[col0], b1hi = b1[16 + col0];
    const int d0p = (tid & 31) * 4, ngp = tid >> 5;           // P6/P8 mapping
    const float4 g4  = *(const float4*)(gma + d0p);
    const float4 be4 = *(const float4*)(bta + d0p);

    // ---- early edge/prior loads (all scalar/float4 values, no arrays) ----
    const int mp = tid & 15, npg = tid >> 4;
    const int n0 = npg * 2, mA = mp, mB = mp + 16;
    float4 e00, e01, e10, e11;
    float  prv00, prv01, prv10, prv11;
    {
        const size_t rowA0 = ((size_t)bt * 32 + n0) * 32;
        const size_t rowA1 = ((size_t)bt * 32 + n0 + 1) * 32;
        e00 = *(const float4*)(edge + (rowA0 + mA) * 4);
        e01 = *(const float4*)(edge + (rowA0 + mB) * 4);
        e10 = *(const float4*)(edge + (rowA1 + mA) * 4);
        e11 = *(const float4*)(edge + (rowA1 + mB) * 4);
        const float* p00 = A_prior + (rowA0 + mA) * 5;
        const float* p01 = A_prior + (rowA0 + mB) * 5;
        const float* p10 = A_prior + (rowA1 + mA) * 5;
        const float* p11 = A_prior + (rowA1 + mB) * 5;
        float q00 = p00[0]*wf0 + p00[1]*wf1 + p00[2]*wf2 + p00[3]*wf3 + p00[4]*wf4;
        float q01 = p01[0]*wf0 + p01[1]*wf1 + p01[2]*wf2 + p01[3]*wf3 + p01[4]*wf4;
        float q10 = p10[0]*wf0 + p10[1]*wf1 + p10[2]*wf2 + p10[3]*wf3 + p10[4]*wf4;
        float q11 = p11[0]*wf0 + p11[1]*wf1 + p11[2]*wf2 + p11[3]*wf3 + p11[4]*wf4;
        if (!(fabsf(q00) < 1e30f)) q00 = 0.f;
        if (!(fabsf(q01) < 1e30f)) q01 = 0.f;
        if (!(fabsf(q10) < 1e30f)) q10 = 0.f;
        if (!(fabsf(q11) < 1e30f)) q11 = 0.f;
        prv00 = rw_ * __logf(fmaxf(q00, 0.f) + 1e-6f);
        prv01 = rw_ * __logf(fmaxf(q01, 0.f) + 1e-6f);
        prv10 = rw_ * __logf(fmaxf(q10, 0.f) + 1e-6f);
        prv11 = rw_ * __logf(fmaxf(q11, 0.f) + 1e-6f);
    }

    if (tid < 32) {
        W1e_s[tid] = *(const float4*)(W1 + (size_t)tid * 260 + 256);
        W2_s[tid]  = W2[tid];
        maskrow[tid] = pad_mask[b_ * 32 + tid] ? 1.f : 0.f;
    }

    // ---- Z staging: pack x -> bf16 A-frags (512 chunks in Qs region) ----
#pragma unroll
    for (int it2 = 0; it2 < 2; ++it2) {
        int f = tid + 256 * it2;                // chunk 0..511
        int lane9 = f & 63, tk = f >> 6;        // tk 0..7
        int nl = (tk >> 2) * 16 + (lane9 & 15); // token 0..31
        int d  = (tk & 3) * 32 + (lane9 >> 4) * 8;
        const float* xr = x + ((size_t)((b_ * 32 + nl) * 64 + t_)) * 128 + d;
        float4 a = *(const float4*)(xr);
        float4 b = *(const float4*)(xr + 4);
        uint4 pk;
        pk.x = pack2(a.x, a.y); pk.y = pack2(a.z, a.w);
        pk.z = pack2(b.x, b.y); pk.w = pack2(b.z, b.w);
        *(uint4*)(Zfrag + f * 8) = pk;
    }
    __syncthreads();

    // ---- A-frags to named scalars; barrier before Qs overwrite ----
    bf16x8 az00 = *(const bf16x8*)(Zfrag + ((0 * 4 + 0) * 64 + lane) * 8);
    bf16x8 az01 = *(const bf16x8*)(Zfrag + ((0 * 4 + 1) * 64 + lane) * 8);
    bf16x8 az02 = *(const bf16x8*)(Zfrag + ((0 * 4 + 2) * 64 + lane) * 8);
    bf16x8 az03 = *(const bf16x8*)(Zfrag + ((0 * 4 + 3) * 64 + lane) * 8);
    bf16x8 az10 = *(const bf16x8*)(Zfrag + ((1 * 4 + 0) * 64 + lane) * 8);
    bf16x8 az11 = *(const bf16x8*)(Zfrag + ((1 * 4 + 1) * 64 + lane) * 8);
    bf16x8 az12 = *(const bf16x8*)(Zfrag + ((1 * 4 + 2) * 64 + lane) * 8);
    bf16x8 az13 = *(const bf16x8*)(Zfrag + ((1 * 4 + 3) * 64 + lane) * 8);
    __syncthreads();

    const bf16x8* WfG = (const bf16x8*)Wfrag;    // all weights from L2-global
    const f32x4 zero = {0.f, 0.f, 0.f, 0.f};

    // ---- projection: per wave nt set {wv, wv+4, ..., wv+24} ----
#pragma unroll
    for (int k7 = 0; k7 < 7; ++k7) {
        const int nt = wv + k7 * 4;             // wave-uniform
        const int cb = ((nt < 24) ? nt * 256 : 8192 + (nt - 24) * 256) + lane;
        bf16x8 bw0 = WfG[cb];
        bf16x8 bw1 = WfG[cb + 64];
        bf16x8 bw2 = WfG[cb + 128];
        bf16x8 bw3 = WfG[cb + 192];
        f32x4 acc0 = zero, acc1 = zero;
        acc0 = __builtin_amdgcn_mfma_f32_16x16x32_bf16(az00, bw0, acc0, 0, 0, 0);
        acc1 = __builtin_amdgcn_mfma_f32_16x16x32_bf16(az10, bw0, acc1, 0, 0, 0);
        acc0 = __builtin_amdgcn_mfma_f32_16x16x32_bf16(az01, bw1, acc0, 0, 0, 0);
        acc1 = __builtin_amdgcn_mfma_f32_16x16x32_bf16(az11, bw1, acc1, 0, 0, 0);
        acc0 = __builtin_amdgcn_mfma_f32_16x16x32_bf16(az02, bw2, acc0, 0, 0, 0);
        acc1 = __builtin_amdgcn_mfma_f32_16x16x32_bf16(az12, bw2, acc1, 0, 0, 0);
        acc0 = __builtin_amdgcn_mfma_f32_16x16x32_bf16(az03, bw3, acc0, 0, 0, 0);
        acc1 = __builtin_amdgcn_mfma_f32_16x16x32_bf16(az13, bw3, acc1, 0, 0, 0);
#pragma unroll
        for (int tg = 0; tg < 2; ++tg) {
            const f32x4 acc = tg ? acc1 : acc0;
            const int tokb = tg * 16 + quad * 4;
#pragma unroll
            for (int reg = 0; reg < 4; ++reg) {
                int tok = tokb + reg;
                float v = acc[reg];
                if (nt < 8)       Qs[tok * 132 + nt * 16 + col0] = v;
                else if (nt < 16) Ks[tok * 132 + (nt - 8) * 16 + col0] = v;
                else if (nt < 24) Vs[tok * 136 + (nt - 16) * 16 + col0] = f2bf(v);
                else if (nt < 26) hqL[tok * 34 + (nt - 24) * 16 + col0] = f2bf(v + (nt == 24 ? b1lo : b1hi));
                else              hkL[tok * 34 + (nt - 26) * 16 + col0] = f2bf(v);
            }
        }
    }
    __syncthreads();

    // ---- P3 + fused softmax (R15-validated): all-scalar accumulators ----
    {
        const float* qa = Qs + n0 * 132;
        const float* qb = qa + 132;
        const float* ka = Ks + mA * 132;
        const float* kb = Ks + mB * 132;
        float a00 = 0.f, a01 = 0.f, a10 = 0.f, a11 = 0.f;
        for (int j = 0; j < 128; j += 4) {
            float4 kva = *(const float4*)(ka + j);
            float4 kvb = *(const float4*)(kb + j);
            float4 qva = *(const float4*)(qa + j);
            float4 qvb = *(const float4*)(qb + j);
            a00 = fmaf(qva.x, kva.x, fmaf(qva.y, kva.y, fmaf(qva.z, kva.z, fmaf(qva.w, kva.w, a00))));
            a01 = fmaf(qva.x, kvb.x, fmaf(qva.y, kvb.y, fmaf(qva.z, kvb.z, fmaf(qva.w, kvb.w, a01))));
            a10 = fmaf(qvb.x, kva.x, fmaf(qvb.y, kva.y, fmaf(qvb.z, kva.z, fmaf(qvb.w, kva.w, a10))));
            a11 = fmaf(qvb.x, kvb.x, fmaf(qvb.y, kvb.y, fmaf(qvb.z, kvb.z, fmaf(qvb.w, kvb.w, a11))));
        }
        float pc00 = 0.f, pc01 = 0.f, pc10 = 0.f, pc11 = 0.f;
#pragma unroll
        for (int h = 0; h < 32; ++h) {
            float4 we = W1e_s[h];
            float w2v = W2_s[h];
            float hq0 = bf2f(hqL[n0 * 34 + h]);
            float hq1 = bf2f(hqL[(n0 + 1) * 34 + h]);
            float hkA = bf2f(hkL[mA * 34 + h]);
            float hkB = bf2f(hkL[mB * 34 + h]);
            float heA0 = fmaf(e00.x, we.x, fmaf(e00.y, we.y, fmaf(e00.z, we.z, e00.w * we.w)));
            float heB0 = fmaf(e01.x, we.x, fmaf(e01.y, we.y, fmaf(e01.z, we.z, e01.w * we.w)));
            float heA1 = fmaf(e10.x, we.x, fmaf(e10.y, we.y, fmaf(e10.z, we.z, e10.w * we.w)));
            float heB1 = fmaf(e11.x, we.x, fmaf(e11.y, we.y, fmaf(e11.z, we.z, e11.w * we.w)));
            pc00 = fmaf(fmaxf(hq0 + hkA + heA0, 0.f), w2v, pc00);
            pc01 = fmaf(fmaxf(hq0 + hkB + heB0, 0.f), w2v, pc01);
            pc10 = fmaf(fmaxf(hq1 + hkA + heA1, 0.f), w2v, pc10);
            pc11 = fmaf(fmaxf(hq1 + hkB + heB1, 0.f), w2v, pc11);
        }
        const float SC = 0.08838834764831845f;
        float lg00 = a00 * SC + pw * (pc00 + b2v) + prv00;
        float lg01 = a01 * SC + pw * (pc01 + b2v) + prv01;
        float lg10 = a10 * SC + pw * (pc10 + b2v) + prv10;
        float lg11 = a11 * SC + pw * (pc11 + b2v) + prv11;
        float mr0 = maskrow[n0], mr1 = maskrow[n0 + 1];
        float mcA = maskrow[mA], mcB = maskrow[mB];
        if (mr0 != 0.f || mcA != 0.f) lg00 = -1e9f;
        if (mr0 != 0.f || mcB != 0.f) lg01 = -1e9f;
        if (mr1 != 0.f || mcA != 0.f) lg10 = -1e9f;
        if (mr1 != 0.f || mcB != 0.f) lg11 = -1e9f;
        // fused row softmax: row n lives across the 16-lane mp-group
        {
            float mx = fmaxf(lg00, lg01);
#pragma unroll
            for (int off = 1; off < 16; off <<= 1)
                mx = fmaxf(mx, __shfl_xor(mx, off, 64));
            float ea = __expf(lg00 - mx);
            float eb = __expf(lg01 - mx);
            float s = ea + eb;
#pragma unroll
            for (int off = 1; off < 16; off <<= 1)
                s += __shfl_xor(s, off, 64);
            float inv = 1.f / s;
            Lg[n0 * 36 + mA] = ea * inv;
            Lg[n0 * 36 + mB] = eb * inv;
        }
        {
            float mx = fmaxf(lg10, lg11);
#pragma unroll
            for (int off = 1; off < 16; off <<= 1)
                mx = fmaxf(mx, __shfl_xor(mx, off, 64));
            float ea = __expf(lg10 - mx);
            float eb = __expf(lg11 - mx);
            float s = ea + eb;
#pragma unroll
            for (int off = 1; off < 16; off <<= 1)
                s += __shfl_xor(s, off, 64);
            float inv = 1.f / s;
            Lg[(n0 + 1) * 36 + mA] = ea * inv;
            Lg[(n0 + 1) * 36 + mB] = eb * inv;
        }
    }
    __syncthreads();

    const int rg = wv & 1, ch = wv >> 1;

    // ---- P6: spatial = alpha @ V (4 rows/thread), all-scalar accumulators --
    {
        const int vks = d0p >> 5, vq = (d0p >> 3) & 3, vj = d0p & 7;
        const int rb = ngp * 4;
        float s00=0.f,s01=0.f,s02=0.f,s03=0.f;
        float s10=0.f,s11=0.f,s12=0.f,s13=0.f;
        float s20=0.f,s21=0.f,s22=0.f,s23=0.f;
        float s30=0.f,s31=0.f,s32=0.f,s33=0.f;
        for (int m = 0; m < 32; m += 4) {
            float4 t0 = *(const float4*)(Lg + (rb + 0) * 36 + m);
            float4 t1 = *(const float4*)(Lg + (rb + 1) * 36 + m);
            float4 t2 = *(const float4*)(Lg + (rb + 2) * 36 + m);
            float4 t3 = *(const float4*)(Lg + (rb + 3) * 36 + m);
            uint2 w0 = *(const uint2*)(Vs + (m + 0) * 136 + d0p);
            uint2 w1 = *(const uint2*)(Vs + (m + 1) * 136 + d0p);
            uint2 w2 = *(const uint2*)(Vs + (m + 2) * 136 + d0p);
            uint2 w3 = *(const uint2*)(Vs + (m + 3) * 136 + d0p);
            {   // mm = 0
                float v0 = bf2f((unsigned short)(w0.x & 0xffffu));
                float v1 = bf2f((unsigned short)(w0.x >> 16));
                float v2 = bf2f((unsigned short)(w0.y & 0xffffu));
                float v3 = bf2f((unsigned short)(w0.y >> 16));
                s00=fmaf(t0.x,v0,s00); s01=fmaf(t0.x,v1,s01); s02=fmaf(t0.x,v2,s02); s03=fmaf(t0.x,v3,s03);
                s10=fmaf(t1.x,v0,s10); s11=fmaf(t1.x,v1,s11); s12=fmaf(t1.x,v2,s12); s13=fmaf(t1.x,v3,s13);
                s20=fmaf(t2.x,v0,s20); s21=fmaf(t2.x,v1,s21); s22=fmaf(t2.x,v2,s22); s23=fmaf(t2.x,v3,s23);
                s30=fmaf(t3.x,v0,s30); s31=fmaf(t3.x,v1,s31); s32=fmaf(t3.x,v2,s32); s33=fmaf(t3.x,v3,s33);
            }
            {   // mm = 1
                float v0 = bf2f((unsigned short)(w1.x & 0xffffu));
                float v1 = bf2f((unsigned short)(w1.x >> 16));
                float v2 = bf2f((unsigned short)(w1.y & 0xffffu));
                float v3 = bf2f((unsigned short)(w1.y >> 16));
                s00=fmaf(t0.y,v0,s00); s01=fmaf(t0.y,v1,s01); s02=fmaf(t0.y,v2,s02); s03=fmaf(t0.y,v3,s03);
                s10=fmaf(t1.y,v0,s10); s11=fmaf(t1.y,v1,s11); s12=fmaf(t1.y,v2,s12); s13=fmaf(t1.y,v3,s13);
                s20=fmaf(t2.y,v0,s20); s21=fmaf(t2.y,v1,s21); s22=fmaf(t2.y,v2,s22); s23=fmaf(t2.y,v3,s23);
                s30=fmaf(t3.y,v0,s30); s31=fmaf(t3.y,v1,s31); s32=fmaf(t3.y,v2,s32); s33=fmaf(t3.y,v3,s33);
            }
            {   // mm = 2
                float v0 = bf2f((unsigned short)(w2.x & 0xffffu));
                float v1 = bf2f((unsigned short)(w2.x >> 16));
                float v2 = bf2f((unsigned short)(w2.y & 0xffffu));
                float v3 = bf2f((unsigned short)(w2.y >> 16));
                s00=fmaf(t0.z,v0,s00); s01=fmaf(t0.z,v1,s01); s02=fmaf(t0.z,v2,s02); s03=fmaf(t0.z,v3,s03);
                s10=fmaf(t1.z,v0,s10); s11=fmaf(t1.z,v1,s11); s12=fmaf(t1.z,v2,s12); s13=fmaf(t1.z,v3,s13);
                s20=fmaf(t2.z,v0,s20); s21=fmaf(t2.z,v1,s21); s22=fmaf(t2.z,v2,s22); s23=fmaf(t2.z,v3,s23);
                s30=fmaf(t3.z,v0,s30); s31=fmaf(t3.z,v1,s31); s32=fmaf(t3.z,v2,s32); s33=fmaf(t3.z,v3,s33);
            }
            {   // mm = 3
                float v0 = bf2f((unsigned short)(w3.x & 0xffffu));
                float v1 = bf2f((unsigned short)(w3.x >> 16));
                float v2 = bf2f((unsigned short)(w3.y & 0xffffu));
                float v3 = bf2f((unsigned short)(w3.y >> 16));
                s00=fmaf(t0.w,v0,s00); s01=fmaf(t0.w,v1,s01); s02=fmaf(t0.w,v2,s02); s03=fmaf(t0.w,v3,s03);
                s10=fmaf(t1.w,v0,s10); s11=fmaf(t1.w,v1,s11); s12=fmaf(t1.w,v2,s12); s13=fmaf(t1.w,v3,s13);
                s20=fmaf(t2.w,v0,s20); s21=fmaf(t2.w,v1,s21); s22=fmaf(t2.w,v2,s22); s23=fmaf(t2.w,v3,s23);
                s30=fmaf(t3.w,v0,s30); s31=fmaf(t3.w,v1,s31); s32=fmaf(t3.w,v2,s32); s33=fmaf(t3.w,v3,s33);
            }
        }
        // Sfrag aliases Ks (dead after P3)
        {
            int nloc = rb + 0; int tg = nloc >> 4, nl = nloc & 15;
            unsigned short* sp = Sfrag + ((tg * 4 + vks) * 64 + vq * 16 + nl) * 8 + vj;
            sp[0] = f2bf(s00); sp[1] = f2bf(s01); sp[2] = f2bf(s02); sp[3] = f2bf(s03);
        }
        {
            int nloc = rb + 1; int tg = nloc >> 4, nl = nloc & 15;
            unsigned short* sp = Sfrag + ((tg * 4 + vks) * 64 + vq * 16 + nl) * 8 + vj;
            sp[0] = f2bf(s10); sp[1] = f2bf(s11); sp[2] = f2bf(s12); sp[3] = f2bf(s13);
        }
        {
            int nloc = rb + 2; int tg = nloc >> 4, nl = nloc & 15;
            unsigned short* sp = Sfrag + ((tg * 4 + vks) * 64 + vq * 16 + nl) * 8 + vj;
            sp[0] = f2bf(s20); sp[1] = f2bf(s21); sp[2] = f2bf(s22); sp[3] = f2bf(s23);
        }
        {
            int nloc = rb + 3; int tg = nloc >> 4, nl = nloc & 15;
            unsigned short* sp = Sfrag + ((tg * 4 + vks) * 64 + vq * 16 + nl) * 8 + vj;
            sp[0] = f2bf(s30); sp[1] = f2bf(s31); sp[2] = f2bf(s32); sp[3] = f2bf(s33);
        }
    }
    __syncthreads();

    // ---- P7: Theta MFMA -> ThOut (alias Qs, stride 132); inline B-frags ----
    {
        f32x4 aT0 = zero, aT1 = zero, aT2 = zero, aT3 = zero;
        bf16x8 av0 = *(const bf16x8*)(Sfrag + ((rg * 4 + 0) * 64 + lane) * 8);
        bf16x8 av1 = *(const bf16x8*)(Sfrag + ((rg * 4 + 1) * 64 + lane) * 8);
        bf16x8 av2 = *(const bf16x8*)(Sfrag + ((rg * 4 + 2) * 64 + lane) * 8);
        bf16x8 av3 = *(const bf16x8*)(Sfrag + ((rg * 4 + 3) * 64 + lane) * 8);
        {
            const int cb = 6144 + ((ch * 4 + 0) * 4) * 64 + lane;
            aT0 = __builtin_amdgcn_mfma_f32_16x16x32_bf16(av0, WfG[cb], aT0, 0, 0, 0);
            aT0 = __builtin_amdgcn_mfma_f32_16x16x32_bf16(av1, WfG[cb + 64], aT0, 0, 0, 0);
            aT0 = __builtin_amdgcn_mfma_f32_16x16x32_bf16(av2, WfG[cb + 128], aT0, 0, 0, 0);
            aT0 = __builtin_amdgcn_mfma_f32_16x16x32_bf16(av3, WfG[cb + 192], aT0, 0, 0, 0);
        }
        {
            const int cb = 6144 + ((ch * 4 + 1) * 4) * 64 + lane;
            aT1 = __builtin_amdgcn_mfma_f32_16x16x32_bf16(av0, WfG[cb], aT1, 0, 0, 0);
            aT1 = __builtin_amdgcn_mfma_f32_16x16x32_bf16(av1, WfG[cb + 64], aT1, 0, 0, 0);
            aT1 = __builtin_amdgcn_mfma_f32_16x16x32_bf16(av2, WfG[cb + 128], aT1, 0, 0, 0);
            aT1 = __builtin_amdgcn_mfma_f32_16x16x32_bf16(av3, WfG[cb + 192], aT1, 0, 0, 0);
        }
        {
            const int cb = 6144 + ((ch * 4 + 2) * 4) * 64 + lane;
            aT2 = __builtin_amdgcn_mfma_f32_16x16x32_bf16(av0, WfG[cb], aT2, 0, 0, 0);
            aT2 = __builtin_amdgcn_mfma_f32_16x16x32_bf16(av1, WfG[cb + 64], aT2, 0, 0, 0);
            aT2 = __builtin_amdgcn_mfma_f32_16x16x32_bf16(av2, WfG[cb + 128], aT2, 0, 0, 0);
            aT2 = __builtin_amdgcn_mfma_f32_16x16x32_bf16(av3, WfG[cb + 192], aT2, 0, 0, 0);
        }
        {
            const int cb = 6144 + ((ch * 4 + 3) * 4) * 64 + lane;
            aT3 = __builtin_amdgcn_mfma_f32_16x16x32_bf16(av0, WfG[cb], aT3, 0, 0, 0);
            aT3 = __builtin_amdgcn_mfma_f32_16x16x32_bf16(av1, WfG[cb + 64], aT3, 0, 0, 0);
            aT3 = __builtin_amdgcn_mfma_f32_16x16x32_bf16(av2, WfG[cb + 128], aT3, 0, 0, 0);
            aT3 = __builtin_amdgcn_mfma_f32_16x16x32_bf16(av3, WfG[cb + 192], aT3, 0, 0, 0);
        }
        const int rbase = rg * 16 + quad * 4;
#pragma unroll
        for (int reg = 0; reg < 4; ++reg) {
            ThOut[(rbase + reg) * 132 + ch * 64 + 0  * 16 + col0] = aT0[reg];
            ThOut[(rbase + reg) * 132 + ch * 64 + 1  * 16 + col0] = aT1[reg];
            ThOut[(rbase + reg) * 132 + ch * 64 + 2  * 16 + col0] = aT2[reg];
            ThOut[(rbase + reg) * 132 + ch * 64 + 3  * 16 + col0] = aT3[reg];
        }
    }
    __syncthreads();

    // ---- P8: y = x + ThOut; LayerNorm; mask; store (4 rows/thread) ----
    {
#pragma unroll
        for (int r = 0; r < 4; ++r) {
            int nloc = ngp * 4 + r;
            const float* xr = x + ((size_t)((b_ * 32 + nloc) * 64 + t_)) * 128 + d0p;
            float4 z  = *(const float4*)(xr);
            float4 th = *(const float4*)(ThOut + nloc * 132 + d0p);
            float y0 = th.x + z.x, y1 = th.y + z.y, y2 = th.z + z.z, y3 = th.w + z.w;
            float s  = (y0 + y1) + (y2 + y3);
            float s2 = (y0*y0 + y1*y1) + (y2*y2 + y3*y3);
#pragma unroll
            for (int off = 1; off < 32; off <<= 1) {
                s  += __shfl_xor(s,  off, 64);
                s2 += __shfl_xor(s2, off, 64);
            }
            float mu   = s * 0.0078125f;
            float var  = s2 * 0.0078125f - mu * mu;
            float rstd = rsqrtf(var + 1e-5f);
            float msk  = (maskrow[nloc] != 0.f) ? 0.f : 1.f;
            float4 o;
            o.x = ((y0 - mu) * rstd * g4.x + be4.x) * msk;
            o.y = ((y1 - mu) * rstd * g4.y + be4.y) * msk;
            o.z = ((y2 - mu) * rstd * g4.z + be4.z) * msk;
            o.w = ((y3 - mu) * rstd * g4.w + be4.w) * msk;
            *(float4*)(out + ((size_t)((b_ * 32 + nloc) * 64 + t_)) * 128 + d0p) = o;
        }
    }
}

// ===========================================================================
extern "C" void kernel_launch(void* const* d_in, const int* in_sizes, int n_in,
                              void* d_out, int out_size, void* d_ws, size_t ws_size,
                              hipStream_t stream) {
    const float* x        = (const float*)d_in[0];
    const float* edge     = (const float*)d_in[1];
    const float* A_prior  = (const float*)d_in[2];
    const unsigned char* pad_mask = (const unsigned char*)d_in[3];
    const float* Wq       = (const float*)d_in[4];
    const float* Wk       = (const float*)d_in[5];
    const float* Wv       = (const float*)d_in[6];
    const float* Theta    = (const float*)d_in[7];
    const float* Wfuse    = (const float*)d_in[8];
    const float* W1       = (const float*)d_in[9];
    const float* b1       = (const float*)d_in[10];
    const float* W2       = (const float*)d_in[11];
    const float* b2       = (const float*)d_in[12];
    const float* gma      = (const float*)d_in[13];
    const float* bta      = (const float*)d_in[14];
    const float* physw    = (const float*)d_in[15];
    const float* priorw   = (const float*)d_in[16];
    float* out = (float*)d_out;

    unsigned short* Wfrag = (unsigned short*)d_ws;   // 147456 B (9216 chunks)

    k0_prep<<<dim3(64), dim3(256), 0, stream>>>(Wq, Wk, Wv, Theta, W1, Wfrag);
    gnn_all<<<dim3(512), dim3(256), 0, stream>>>(
        x, edge, A_prior, pad_mask, Wfrag, Wfuse,
        W1, b1, W2, b2, gma, bta, physw, priorw, out);
}

// Round 8
// 125.900 us; speedup vs baseline: 2.6366x; 1.0027x over previous
//
#include <hip/hip_runtime.h>

// B=8, N=32, T=64, D=128, E=4, H=32, BT=512
// R17: algebraic phase deletion on the R16 scalar-purged base (126us total;
// gnn_all now below the harness's 43us fill kernels in top-5 -- scratch was
// rule-#20 array demotion, confirmed).  out_f = (alpha@V)@Theta^T
// = alpha @ (Z @ (Theta@Wv)^T): k0_prep precomputes M = Theta@Wv into the
// Wv frag slot; projection emits C = Z@M^T (same code); P7 (Theta MFMA +
// 16 L2 loads + Sfrag round-trip) is DELETED, and since P6's (row,col)
// thread mapping == P8's, spatial accumulators feed LayerNorm directly in
// registers (ThOut round-trip deleted too). Barriers 8 -> 4. Also: paired
// uint LDS reads for hq/hk in P3 (halves LDS issues), x prefetch before the
// P6 m-loop. Zero local aggregates anywhere (R16 lesson).

typedef __bf16 bf16x8 __attribute__((ext_vector_type(8)));
typedef float  f32x4  __attribute__((ext_vector_type(4)));

static __device__ __forceinline__ unsigned short f2bf(float f) {
    unsigned u = __float_as_uint(f);
    u += 0x7fffu + ((u >> 16) & 1u);        // RNE
    return (unsigned short)(u >> 16);
}
static __device__ __forceinline__ float bf2f(unsigned short u) {
    return __uint_as_float(((unsigned)u) << 16);
}
static __device__ __forceinline__ unsigned pack2(float a, float b) {
    return (unsigned)f2bf(a) | ((unsigned)f2bf(b) << 16);
}

// ---------------------------------------------------------------------------
// Wfrag (16B chunks): [0,2048) Wq | [2048,4096) Wk | [4096,6144) M=Theta@Wv |
// chunk 8192+: Cq=W1q@Wq (512), chunk 8704+: Ck=W1k@Wk (512).
// B-frag chunk (nt*4+ks)*64+lane holds B[k=j][n]: n = nt*16+(lane&15),
// j = ks*32+(lane>>4)*8 + (0..7).  ([6144,8192) Theta slot now unused.)
// ---------------------------------------------------------------------------

__global__ __launch_bounds__(256) void k0_prep(
    const float* __restrict__ Wq, const float* __restrict__ Wk,
    const float* __restrict__ Wv, const float* __restrict__ Theta,
    const float* __restrict__ W1, unsigned short* __restrict__ Wfrag)
{
    const int tid = threadIdx.x;
    const int blk = blockIdx.x;
    if (blk < 16) {
        // pack Wq (blocks 0..7), Wk (8..15) to bf16 B-frags
        int gid = blk * 256 + tid;             // 0..4095
        int g = gid >> 11, c = gid & 2047;
        int ntk = c >> 6, lane = c & 63;
        int i = (ntk >> 2) * 16 + (lane & 15);
        int j = (ntk & 3) * 32 + (lane >> 4) * 8;
        const float* src = (g == 0 ? Wq : Wk) + (size_t)i * 128 + j;
        float4 a = *(const float4*)(src);
        float4 b = *(const float4*)(src + 4);
        uint4 pk;
        pk.x = pack2(a.x, a.y); pk.y = pack2(a.z, a.w);
        pk.z = pack2(b.x, b.y); pk.w = pack2(b.z, b.w);
        *(uint4*)(Wfrag + (size_t)gid * 8) = pk;
    } else if (blk < 48) {
        // compose Cq = W1q@Wq, Ck = W1k@Wk
        int b2 = blk - 16;                     // 0..31
        int mat = b2 & 1;
        int hbase = (b2 >> 1) * 2;
        int hl = tid >> 7, col = tid & 127;
        int h = hbase + hl;
        const float* Wsel = mat ? Wk : Wq;
        const float* w1r = W1 + (size_t)h * 260 + mat * 128;
        float acc = 0.f;
        for (int i = 0; i < 128; ++i)
            acc = fmaf(w1r[i], Wsel[(size_t)i * 128 + col], acc);
        int nt = h >> 4;
        unsigned base = 65536u + (unsigned)mat * 4096u;   // shorts
        int lane = (h & 15) | (((col >> 3) & 3) << 4);
        int ks = col >> 5, vj = col & 7;
        Wfrag[base + (unsigned)((nt * 4 + ks) * 64 + lane) * 8 + vj] = f2bf(acc);
    } else {
        // compose M = Theta @ Wv into the Wv frag slot [4096,6144)
        // M[i][j] = sum_k Theta[i][k] * Wv[k][j]   (i = out-dim, j = Z-k-dim)
        int b2 = blk - 48;                     // 0..31
        int i  = b2 * 4 + (tid >> 6);          // row 0..127
        int j0 = (tid & 63) * 2;
        const float* trow = Theta + (size_t)i * 128;
        float m0 = 0.f, m1 = 0.f;
        for (int k = 0; k < 128; ++k) {
            float tv = trow[k];
            m0 = fmaf(tv, Wv[(size_t)k * 128 + j0], m0);
            m1 = fmaf(tv, Wv[(size_t)k * 128 + j0 + 1], m1);
        }
        {
            int jj = j0;
            int ntk = (i >> 4) * 4 + (jj >> 5);
            int lane = (i & 15) | (((jj >> 3) & 3) << 4);
            Wfrag[(unsigned)((4096 + ntk * 64 + lane) * 8 + (jj & 7))] = f2bf(m0);
        }
        {
            int jj = j0 + 1;
            int ntk = (i >> 4) * 4 + (jj >> 5);
            int lane = (i & 15) | (((jj >> 3) & 3) << 4);
            Wfrag[(unsigned)((4096 + ntk * 64 + lane) * 8 + (jj & 7))] = f2bf(m1);
        }
    }
}

// ===== fully fused: grid 512 (1 bt/block), 256 threads, (256,2) =============
// Arena (52224 B), same layout as R16; Vs now holds C = Z@M^T (bf16).
__global__ __launch_bounds__(256, 2)
void gnn_all(const float* __restrict__ x, const float* __restrict__ edge,
             const float* __restrict__ A_prior, const unsigned char* __restrict__ pad_mask,
             const unsigned short* __restrict__ Wfrag, const float* __restrict__ Wfuse,
             const float* __restrict__ W1, const float* __restrict__ b1,
             const float* __restrict__ W2, const float* __restrict__ b2,
             const float* __restrict__ gma, const float* __restrict__ bta,
             const float* __restrict__ physw, const float* __restrict__ priorw,
             float* __restrict__ out)
{
    __shared__ __align__(16) unsigned char arena[52224];
    float*          Qs    = (float*)arena;
    unsigned short* Zfrag = (unsigned short*)arena;           // pre-projection
    float*          Ks    = (float*)(arena + 16896);
    unsigned short* Vs    = (unsigned short*)(arena + 33792); // C tile [32][136]
    float*          Lg    = (float*)(arena + 42496);          // [32][36]
    unsigned short* hqL   = (unsigned short*)(arena + 47104);
    unsigned short* hkL   = (unsigned short*)(arena + 49280);
    float4*         W1e_s = (float4*)(arena + 51456);
    float*          W2_s  = (float*)(arena + 51968);
    float*          maskrow = (float*)(arena + 52096);

    const int tid = threadIdx.x;
    const int bt  = blockIdx.x;
    const int b_  = bt >> 6, t_ = bt & 63;

    const float pw  = physw[0];
    const float rw_ = priorw[0];
    const float b2v = b2[0];
    const float wf0 = Wfuse[0], wf1 = Wfuse[1], wf2 = Wfuse[2],
                wf3 = Wfuse[3], wf4 = Wfuse[4];

    const int wv = tid >> 6, lane = tid & 63;
    const int quad = lane >> 4, col0 = lane & 15;
    const float b1lo = b1[col0], b1hi = b1[16 + col0];
    const int d0p = (tid & 31) * 4, ngp = tid >> 5;           // P6/P8 mapping
    const float4 g4  = *(const float4*)(gma + d0p);
    const float4 be4 = *(const float4*)(bta + d0p);

    // ---- early edge/prior loads (scalars only) ----
    const int mp = tid & 15, npg = tid >> 4;
    const int n0 = npg * 2, mA = mp, mB = mp + 16;
    float4 e00, e01, e10, e11;
    float  prv00, prv01, prv10, prv11;
    {
        const size_t rowA0 = ((size_t)bt * 32 + n0) * 32;
        const size_t rowA1 = ((size_t)bt * 32 + n0 + 1) * 32;
        e00 = *(const float4*)(edge + (rowA0 + mA) * 4);
        e01 = *(const float4*)(edge + (rowA0 + mB) * 4);
        e10 = *(const float4*)(edge + (rowA1 + mA) * 4);
        e11 = *(const float4*)(edge + (rowA1 + mB) * 4);
        const float* p00 = A_prior + (rowA0 + mA) * 5;
        const float* p01 = A_prior + (rowA0 + mB) * 5;
        const float* p10 = A_prior + (rowA1 + mA) * 5;
        const float* p11 = A_prior + (rowA1 + mB) * 5;
        float q00 = p00[0]*wf0 + p00[1]*wf1 + p00[2]*wf2 + p00[3]*wf3 + p00[4]*wf4;
        float q01 = p01[0]*wf0 + p01[1]*wf1 + p01[2]*wf2 + p01[3]*wf3 + p01[4]*wf4;
        float q10 = p10[0]*wf0 + p10[1]*wf1 + p10[2]*wf2 + p10[3]*wf3 + p10[4]*wf4;
        float q11 = p11[0]*wf0 + p11[1]*wf1 + p11[2]*wf2 + p11[3]*wf3 + p11[4]*wf4;
        if (!(fabsf(q00) < 1e30f)) q00 = 0.f;
        if (!(fabsf(q01) < 1e30f)) q01 = 0.f;
        if (!(fabsf(q10) < 1e30f)) q10 = 0.f;
        if (!(fabsf(q11) < 1e30f)) q11 = 0.f;
        prv00 = rw_ * __logf(fmaxf(q00, 0.f) + 1e-6f);
        prv01 = rw_ * __logf(fmaxf(q01, 0.f) + 1e-6f);
        prv10 = rw_ * __logf(fmaxf(q10, 0.f) + 1e-6f);
        prv11 = rw_ * __logf(fmaxf(q11, 0.f) + 1e-6f);
    }

    if (tid < 32) {
        W1e_s[tid] = *(const float4*)(W1 + (size_t)tid * 260 + 256);
        W2_s[tid]  = W2[tid];
        maskrow[tid] = pad_mask[b_ * 32 + tid] ? 1.f : 0.f;
    }

    // ---- Z staging: pack x -> bf16 A-frags (512 chunks in Qs region) ----
#pragma unroll
    for (int it2 = 0; it2 < 2; ++it2) {
        int f = tid + 256 * it2;                // chunk 0..511
        int lane9 = f & 63, tk = f >> 6;        // tk 0..7
        int nl = (tk >> 2) * 16 + (lane9 & 15); // token 0..31
        int d  = (tk & 3) * 32 + (lane9 >> 4) * 8;
        const float* xr = x + ((size_t)((b_ * 32 + nl) * 64 + t_)) * 128 + d;
        float4 a = *(const float4*)(xr);
        float4 b = *(const float4*)(xr + 4);
        uint4 pk;
        pk.x = pack2(a.x, a.y); pk.y = pack2(a.z, a.w);
        pk.z = pack2(b.x, b.y); pk.w = pack2(b.z, b.w);
        *(uint4*)(Zfrag + f * 8) = pk;
    }
    __syncthreads();

    // ---- A-frags to named scalars; barrier before Qs overwrite ----
    bf16x8 az00 = *(const bf16x8*)(Zfrag + ((0 * 4 + 0) * 64 + lane) * 8);
    bf16x8 az01 = *(const bf16x8*)(Zfrag + ((0 * 4 + 1) * 64 + lane) * 8);
    bf16x8 az02 = *(const bf16x8*)(Zfrag + ((0 * 4 + 2) * 64 + lane) * 8);
    bf16x8 az03 = *(const bf16x8*)(Zfrag + ((0 * 4 + 3) * 64 + lane) * 8);
    bf16x8 az10 = *(const bf16x8*)(Zfrag + ((1 * 4 + 0) * 64 + lane) * 8);
    bf16x8 az11 = *(const bf16x8*)(Zfrag + ((1 * 4 + 1) * 64 + lane) * 8);
    bf16x8 az12 = *(const bf16x8*)(Zfrag + ((1 * 4 + 2) * 64 + lane) * 8);
    bf16x8 az13 = *(const bf16x8*)(Zfrag + ((1 * 4 + 3) * 64 + lane) * 8);
    __syncthreads();

    const bf16x8* WfG = (const bf16x8*)Wfrag;
    const f32x4 zero = {0.f, 0.f, 0.f, 0.f};

    // ---- projection: Q|K|C|hq|hk; per wave nt set {wv, wv+4, ..., wv+24} ----
#pragma unroll
    for (int k7 = 0; k7 < 7; ++k7) {
        const int nt = wv + k7 * 4;             // wave-uniform
        const int cb = ((nt < 24) ? nt * 256 : 8192 + (nt - 24) * 256) + lane;
        bf16x8 bw0 = WfG[cb];
        bf16x8 bw1 = WfG[cb + 64];
        bf16x8 bw2 = WfG[cb + 128];
        bf16x8 bw3 = WfG[cb + 192];
        f32x4 acc0 = zero, acc1 = zero;
        acc0 = __builtin_amdgcn_mfma_f32_16x16x32_bf16(az00, bw0, acc0, 0, 0, 0);
        acc1 = __builtin_amdgcn_mfma_f32_16x16x32_bf16(az10, bw0, acc1, 0, 0, 0);
        acc0 = __builtin_amdgcn_mfma_f32_16x16x32_bf16(az01, bw1, acc0, 0, 0, 0);
        acc1 = __builtin_amdgcn_mfma_f32_16x16x32_bf16(az11, bw1, acc1, 0, 0, 0);
        acc0 = __builtin_amdgcn_mfma_f32_16x16x32_bf16(az02, bw2, acc0, 0, 0, 0);
        acc1 = __builtin_amdgcn_mfma_f32_16x16x32_bf16(az12, bw2, acc1, 0, 0, 0);
        acc0 = __builtin_amdgcn_mfma_f32_16x16x32_bf16(az03, bw3, acc0, 0, 0, 0);
        acc1 = __builtin_amdgcn_mfma_f32_16x16x32_bf16(az13, bw3, acc1, 0, 0, 0);
#pragma unroll
        for (int tg = 0; tg < 2; ++tg) {
            const f32x4 acc = tg ? acc1 : acc0;
            const int tokb = tg * 16 + quad * 4;
#pragma unroll
            for (int reg = 0; reg < 4; ++reg) {
                int tok = tokb + reg;
                float v = acc[reg];
                if (nt < 8)       Qs[tok * 132 + nt * 16 + col0] = v;
                else if (nt < 16) Ks[tok * 132 + (nt - 8) * 16 + col0] = v;
                else if (nt < 24) Vs[tok * 136 + (nt - 16) * 16 + col0] = f2bf(v);
                else if (nt < 26) hqL[tok * 34 + (nt - 24) * 16 + col0] = f2bf(v + (nt == 24 ? b1lo : b1hi));
                else              hkL[tok * 34 + (nt - 26) * 16 + col0] = f2bf(v);
            }
        }
    }
    __syncthreads();

    // ---- P3 + fused softmax (scalar; paired uint hq/hk reads) ----
    {
        const float* qa = Qs + n0 * 132;
        const float* qb = qa + 132;
        const float* ka = Ks + mA * 132;
        const float* kb = Ks + mB * 132;
        float a00 = 0.f, a01 = 0.f, a10 = 0.f, a11 = 0.f;
        for (int j = 0; j < 128; j += 4) {
            float4 kva = *(const float4*)(ka + j);
            float4 kvb = *(const float4*)(kb + j);
            float4 qva = *(const float4*)(qa + j);
            float4 qvb = *(const float4*)(qb + j);
            a00 = fmaf(qva.x, kva.x, fmaf(qva.y, kva.y, fmaf(qva.z, kva.z, fmaf(qva.w, kva.w, a00))));
            a01 = fmaf(qva.x, kvb.x, fmaf(qva.y, kvb.y, fmaf(qva.z, kvb.z, fmaf(qva.w, kvb.w, a01))));
            a10 = fmaf(qvb.x, kva.x, fmaf(qvb.y, kva.y, fmaf(qvb.z, kva.z, fmaf(qvb.w, kva.w, a10))));
            a11 = fmaf(qvb.x, kvb.x, fmaf(qvb.y, kvb.y, fmaf(qvb.z, kvb.z, fmaf(qvb.w, kvb.w, a11))));
        }
        // rows are 4B-aligned: row stride = 34 shorts = 68 B (68 % 4 == 0)
        const unsigned* hq0p = (const unsigned*)(hqL + n0 * 34);
        const unsigned* hq1p = (const unsigned*)(hqL + (n0 + 1) * 34);
        const unsigned* hkAp = (const unsigned*)(hkL + mA * 34);
        const unsigned* hkBp = (const unsigned*)(hkL + mB * 34);
        float pc00 = 0.f, pc01 = 0.f, pc10 = 0.f, pc11 = 0.f;
#pragma unroll
        for (int h2 = 0; h2 < 16; ++h2) {
            unsigned uq0 = hq0p[h2], uq1 = hq1p[h2];
            unsigned ukA = hkAp[h2], ukB = hkBp[h2];
#pragma unroll
            for (int hb = 0; hb < 2; ++hb) {
                int h = h2 * 2 + hb;
                float4 we = W1e_s[h];
                float w2v = W2_s[h];
                float hq0 = bf2f((unsigned short)(hb ? (uq0 >> 16) : (uq0 & 0xffffu)));
                float hq1 = bf2f((unsigned short)(hb ? (uq1 >> 16) : (uq1 & 0xffffu)));
                float hkA = bf2f((unsigned short)(hb ? (ukA >> 16) : (ukA & 0xffffu)));
                float hkB = bf2f((unsigned short)(hb ? (ukB >> 16) : (ukB & 0xffffu)));
                float heA0 = fmaf(e00.x, we.x, fmaf(e00.y, we.y, fmaf(e00.z, we.z, e00.w * we.w)));
                float heB0 = fmaf(e01.x, we.x, fmaf(e01.y, we.y, fmaf(e01.z, we.z, e01.w * we.w)));
                float heA1 = fmaf(e10.x, we.x, fmaf(e10.y, we.y, fmaf(e10.z, we.z, e10.w * we.w)));
                float heB1 = fmaf(e11.x, we.x, fmaf(e11.y, we.y, fmaf(e11.z, we.z, e11.w * we.w)));
                pc00 = fmaf(fmaxf(hq0 + hkA + heA0, 0.f), w2v, pc00);
                pc01 = fmaf(fmaxf(hq0 + hkB + heB0, 0.f), w2v, pc01);
                pc10 = fmaf(fmaxf(hq1 + hkA + heA1, 0.f), w2v, pc10);
                pc11 = fmaf(fmaxf(hq1 + hkB + heB1, 0.f), w2v, pc11);
            }
        }
        const float SC = 0.08838834764831845f;
        float lg00 = a00 * SC + pw * (pc00 + b2v) + prv00;
        float lg01 = a01 * SC + pw * (pc01 + b2v) + prv01;
        float lg10 = a10 * SC + pw * (pc10 + b2v) + prv10;
        float lg11 = a11 * SC + pw * (pc11 + b2v) + prv11;
        float mr0 = maskrow[n0], mr1 = maskrow[n0 + 1];
        float mcA = maskrow[mA], mcB = maskrow[mB];
        if (mr0 != 0.f || mcA != 0.f) lg00 = -1e9f;
        if (mr0 != 0.f || mcB != 0.f) lg01 = -1e9f;
        if (mr1 != 0.f || mcA != 0.f) lg10 = -1e9f;
        if (mr1 != 0.f || mcB != 0.f) lg11 = -1e9f;
        // fused row softmax: row n lives across the 16-lane mp-group
        {
            float mx = fmaxf(lg00, lg01);
#pragma unroll
            for (int off = 1; off < 16; off <<= 1)
                mx = fmaxf(mx, __shfl_xor(mx, off, 64));
            float ea = __expf(lg00 - mx);
            float eb = __expf(lg01 - mx);
            float s = ea + eb;
#pragma unroll
            for (int off = 1; off < 16; off <<= 1)
                s += __shfl_xor(s, off, 64);
            float inv = 1.f / s;
            Lg[n0 * 36 + mA] = ea * inv;
            Lg[n0 * 36 + mB] = eb * inv;
        }
        {
            float mx = fmaxf(lg10, lg11);
#pragma unroll
            for (int off = 1; off < 16; off <<= 1)
                mx = fmaxf(mx, __shfl_xor(mx, off, 64));
            float ea = __expf(lg10 - mx);
            float eb = __expf(lg11 - mx);
            float s = ea + eb;
#pragma unroll
            for (int off = 1; off < 16; off <<= 1)
                s += __shfl_xor(s, off, 64);
            float inv = 1.f / s;
            Lg[(n0 + 1) * 36 + mA] = ea * inv;
            Lg[(n0 + 1) * 36 + mB] = eb * inv;
        }
    }
    __syncthreads();

    // ---- P6+P8 merged: out_f = alpha @ C accumulated in regs, then
    //      y = x + out_f, LayerNorm, mask, store. No LDS round-trip. ----
    {
        const int rb = ngp * 4;
        // x prefetch (in flight under the m-loop)
        float4 xp0 = *(const float4*)(x + ((size_t)((b_ * 32 + rb + 0) * 64 + t_)) * 128 + d0p);
        float4 xp1 = *(const float4*)(x + ((size_t)((b_ * 32 + rb + 1) * 64 + t_)) * 128 + d0p);
        float4 xp2 = *(const float4*)(x + ((size_t)((b_ * 32 + rb + 2) * 64 + t_)) * 128 + d0p);
        float4 xp3 = *(const float4*)(x + ((size_t)((b_ * 32 + rb + 3) * 64 + t_)) * 128 + d0p);

        float s00=0.f,s01=0.f,s02=0.f,s03=0.f;
        float s10=0.f,s11=0.f,s12=0.f,s13=0.f;
        float s20=0.f,s21=0.f,s22=0.f,s23=0.f;
        float s30=0.f,s31=0.f,s32=0.f,s33=0.f;
        for (int m = 0; m < 32; m += 4) {
            float4 t0 = *(const float4*)(Lg + (rb + 0) * 36 + m);
            float4 t1 = *(const float4*)(Lg + (rb + 1) * 36 + m);
            float4 t2 = *(const float4*)(Lg + (rb + 2) * 36 + m);
            float4 t3 = *(const float4*)(Lg + (rb + 3) * 36 + m);
            uint2 w0 = *(const uint2*)(Vs + (m + 0) * 136 + d0p);
            uint2 w1 = *(const uint2*)(Vs + (m + 1) * 136 + d0p);
            uint2 w2 = *(const uint2*)(Vs + (m + 2) * 136 + d0p);
            uint2 w3 = *(const uint2*)(Vs + (m + 3) * 136 + d0p);
            {   // mm = 0
                float v0 = bf2f((unsigned short)(w0.x & 0xffffu));
                float v1 = bf2f((unsigned short)(w0.x >> 16));
                float v2 = bf2f((unsigned short)(w0.y & 0xffffu));
                float v3 = bf2f((unsigned short)(w0.y >> 16));
                s00=fmaf(t0.x,v0,s00); s01=fmaf(t0.x,v1,s01); s02=fmaf(t0.x,v2,s02); s03=fmaf(t0.x,v3,s03);
                s10=fmaf(t1.x,v0,s10); s11=fmaf(t1.x,v1,s11); s12=fmaf(t1.x,v2,s12); s13=fmaf(t1.x,v3,s13);
                s20=fmaf(t2.x,v0,s20); s21=fmaf(t2.x,v1,s21); s22=fmaf(t2.x,v2,s22); s23=fmaf(t2.x,v3,s23);
                s30=fmaf(t3.x,v0,s30); s31=fmaf(t3.x,v1,s31); s32=fmaf(t3.x,v2,s32); s33=fmaf(t3.x,v3,s33);
            }
            {   // mm = 1
                float v0 = bf2f((unsigned short)(w1.x & 0xffffu));
                float v1 = bf2f((unsigned short)(w1.x >> 16));
                float v2 = bf2f((unsigned short)(w1.y & 0xffffu));
                float v3 = bf2f((unsigned short)(w1.y >> 16));
                s00=fmaf(t0.y,v0,s00); s01=fmaf(t0.y,v1,s01); s02=fmaf(t0.y,v2,s02); s03=fmaf(t0.y,v3,s03);
                s10=fmaf(t1.y,v0,s10); s11=fmaf(t1.y,v1,s11); s12=fmaf(t1.y,v2,s12); s13=fmaf(t1.y,v3,s13);
                s20=fmaf(t2.y,v0,s20); s21=fmaf(t2.y,v1,s21); s22=fmaf(t2.y,v2,s22); s23=fmaf(t2.y,v3,s23);
                s30=fmaf(t3.y,v0,s30); s31=fmaf(t3.y,v1,s31); s32=fmaf(t3.y,v2,s32); s33=fmaf(t3.y,v3,s33);
            }
            {   // mm = 2
                float v0 = bf2f((unsigned short)(w2.x & 0xffffu));
                float v1 = bf2f((unsigned short)(w2.x >> 16));
                float v2 = bf2f((unsigned short)(w2.y & 0xffffu));
                float v3 = bf2f((unsigned short)(w2.y >> 16));
                s00=fmaf(t0.z,v0,s00); s01=fmaf(t0.z,v1,s01); s02=fmaf(t0.z,v2,s02); s03=fmaf(t0.z,v3,s03);
                s10=fmaf(t1.z,v0,s10); s11=fmaf(t1.z,v1,s11); s12=fmaf(t1.z,v2,s12); s13=fmaf(t1.z,v3,s13);
                s20=fmaf(t2.z,v0,s20); s21=fmaf(t2.z,v1,s21); s22=fmaf(t2.z,v2,s22); s23=fmaf(t2.z,v3,s23);
                s30=fmaf(t3.z,v0,s30); s31=fmaf(t3.z,v1,s31); s32=fmaf(t3.z,v2,s32); s33=fmaf(t3.z,v3,s33);
            }
            {   // mm = 3
                float v0 = bf2f((unsigned short)(w3.x & 0xffffu));
                float v1 = bf2f((unsigned short)(w3.x >> 16));
                float v2 = bf2f((unsigned short)(w3.y & 0xffffu));
                float v3 = bf2f((unsigned short)(w3.y >> 16));
                s00=fmaf(t0.w,v0,s00); s01=fmaf(t0.w,v1,s01); s02=fmaf(t0.w,v2,s02); s03=fmaf(t0.w,v3,s03);
                s10=fmaf(t1.w,v0,s10); s11=fmaf(t1.w,v1,s11); s12=fmaf(t1.w,v2,s12); s13=fmaf(t1.w,v3,s13);
                s20=fmaf(t2.w,v0,s20); s21=fmaf(t2.w,v1,s21); s22=fmaf(t2.w,v2,s22); s23=fmaf(t2.w,v3,s23);
                s30=fmaf(t3.w,v0,s30); s31=fmaf(t3.w,v1,s31); s32=fmaf(t3.w,v2,s32); s33=fmaf(t3.w,v3,s33);
            }
        }

        // ---- LayerNorm + mask + store, row r uses (xp_r, s_r*) directly ----
        {
            float y0 = s00 + xp0.x, y1 = s01 + xp0.y, y2 = s02 + xp0.z, y3 = s03 + xp0.w;
            float s  = (y0 + y1) + (y2 + y3);
            float s2 = (y0*y0 + y1*y1) + (y2*y2 + y3*y3);
#pragma unroll
            for (int off = 1; off < 32; off <<= 1) { s += __shfl_xor(s, off, 64); s2 += __shfl_xor(s2, off, 64); }
            float mu = s * 0.0078125f, var = s2 * 0.0078125f - mu * mu;
            float rstd = rsqrtf(var + 1e-5f);
            float msk = (maskrow[rb + 0] != 0.f) ? 0.f : 1.f;
            float4 o;
            o.x = ((y0 - mu) * rstd * g4.x + be4.x) * msk;
            o.y = ((y1 - mu) * rstd * g4.y + be4.y) * msk;
            o.z = ((y2 - mu) * rstd * g4.z + be4.z) * msk;
            o.w = ((y3 - mu) * rstd * g4.w + be4.w) * msk;
            *(float4*)(out + ((size_t)((b_ * 32 + rb + 0) * 64 + t_)) * 128 + d0p) = o;
        }
        {
            float y0 = s10 + xp1.x, y1 = s11 + xp1.y, y2 = s12 + xp1.z, y3 = s13 + xp1.w;
            float s  = (y0 + y1) + (y2 + y3);
            float s2 = (y0*y0 + y1*y1) + (y2*y2 + y3*y3);
#pragma unroll
            for (int off = 1; off < 32; off <<= 1) { s += __shfl_xor(s, off, 64); s2 += __shfl_xor(s2, off, 64); }
            float mu = s * 0.0078125f, var = s2 * 0.0078125f - mu * mu;
            float rstd = rsqrtf(var + 1e-5f);
            float msk = (maskrow[rb + 1] != 0.f) ? 0.f : 1.f;
            float4 o;
            o.x = ((y0 - mu) * rstd * g4.x + be4.x) * msk;
            o.y = ((y1 - mu) * rstd * g4.y + be4.y) * msk;
            o.z = ((y2 - mu) * rstd * g4.z + be4.z) * msk;
            o.w = ((y3 - mu) * rstd * g4.w + be4.w) * msk;
            *(float4*)(out + ((size_t)((b_ * 32 + rb + 1) * 64 + t_)) * 128 + d0p) = o;
        }
        {
            float y0 = s20 + xp2.x, y1 = s21 + xp2.y, y2 = s22 + xp2.z, y3 = s23 + xp2.w;
            float s  = (y0 + y1) + (y2 + y3);
            float s2 = (y0*y0 + y1*y1) + (y2*y2 + y3*y3);
#pragma unroll
            for (int off = 1; off < 32; off <<= 1) { s += __shfl_xor(s, off, 64); s2 += __shfl_xor(s2, off, 64); }
            float mu = s * 0.0078125f, var = s2 * 0.0078125f - mu * mu;
            float rstd = rsqrtf(var + 1e-5f);
            float msk = (maskrow[rb + 2] != 0.f) ? 0.f : 1.f;
            float4 o;
            o.x = ((y0 - mu) * rstd * g4.x + be4.x) * msk;
            o.y = ((y1 - mu) * rstd * g4.y + be4.y) * msk;
            o.z = ((y2 - mu) * rstd * g4.z + be4.z) * msk;
            o.w = ((y3 - mu) * rstd * g4.w + be4.w) * msk;
            *(float4*)(out + ((size_t)((b_ * 32 + rb + 2) * 64 + t_)) * 128 + d0p) = o;
        }
        {
            float y0 = s30 + xp3.x, y1 = s31 + xp3.y, y2 = s32 + xp3.z, y3 = s33 + xp3.w;
            float s  = (y0 + y1) + (y2 + y3);
            float s2 = (y0*y0 + y1*y1) + (y2*y2 + y3*y3);
#pragma unroll
            for (int off = 1; off < 32; off <<= 1) { s += __shfl_xor(s, off, 64); s2 += __shfl_xor(s2, off, 64); }
            float mu = s * 0.0078125f, var = s2 * 0.0078125f - mu * mu;
            float rstd = rsqrtf(var + 1e-5f);
            float msk = (maskrow[rb + 3] != 0.f) ? 0.f : 1.f;
            float4 o;
            o.x = ((y0 - mu) * rstd * g4.x + be4.x) * msk;
            o.y = ((y1 - mu) * rstd * g4.y + be4.y) * msk;
            o.z = ((y2 - mu) * rstd * g4.z + be4.z) * msk;
            o.w = ((y3 - mu) * rstd * g4.w + be4.w) * msk;
            *(float4*)(out + ((size_t)((b_ * 32 + rb + 3) * 64 + t_)) * 128 + d0p) = o;
        }
    }
}

// ===========================================================================
extern "C" void kernel_launch(void* const* d_in, const int* in_sizes, int n_in,
                              void* d_out, int out_size, void* d_ws, size_t ws_size,
                              hipStream_t stream) {
    const float* x        = (const float*)d_in[0];
    const float* edge     = (const float*)d_in[1];
    const float* A_prior  = (const float*)d_in[2];
    const unsigned char* pad_mask = (const unsigned char*)d_in[3];
    const float* Wq       = (const float*)d_in[4];
    const float* Wk       = (const float*)d_in[5];
    const float* Wv       = (const float*)d_in[6];
    const float* Theta    = (const float*)d_in[7];
    const float* Wfuse    = (const float*)d_in[8];
    const float* W1       = (const float*)d_in[9];
    const float* b1       = (const float*)d_in[10];
    const float* W2       = (const float*)d_in[11];
    const float* b2       = (const float*)d_in[12];
    const float* gma      = (const float*)d_in[13];
    const float* bta      = (const float*)d_in[14];
    const float* physw    = (const float*)d_in[15];
    const float* priorw   = (const float*)d_in[16];
    float* out = (float*)d_out;

    unsigned short* Wfrag = (unsigned short*)d_ws;   // 147456 B (9216 chunks)

    k0_prep<<<dim3(80), dim3(256), 0, stream>>>(Wq, Wk, Wv, Theta, W1, Wfrag);
    gnn_all<<<dim3(512), dim3(256), 0, stream>>>(
        x, edge, A_prior, pad_mask, Wfrag, Wfuse,
        W1, b1, W2, b2, gma, bta, physw, priorw, out);
}